// Round 1
// baseline (997.106 us; speedup 1.0000x reference)
//
#include <hip/hip_runtime.h>
#include <cstdint>

typedef unsigned short u16;
typedef __attribute__((ext_vector_type(8))) short  short8;   // 8 bf16 in 4 VGPRs
typedef __attribute__((ext_vector_type(4))) float  f32x4;

#define BN 2
#define NN 16384
#define FH 64
#define FW 64
#define GH 256
#define GW 256
#define CC 128
#define K0P 416              // 386 padded to 13*32
#define M_TOTAL (4*BN*NN)    // 131072

// LDS strides in u16 elements; byte stride % 32 == 16 -> 2-way banks on b128 (free, m136)
#define SX 424
#define S1 1032
#define S2 520
#define S3 264
#define S4 136
#define OX 0
#define O1 (32*SX)            // 13568
#define O2 (O1 + 32*S1)       // 46592
#define LDS_ELEMS (O2 + 32*S2) // 63232 u16 = 126464 B

__device__ __forceinline__ u16 f2bf(float f) {
  union { float f; uint32_t u; } v; v.f = f;
  uint32_t r = (v.u + 0x7fffu + ((v.u >> 16) & 1u)) >> 16;
  return (u16)r;
}
__device__ __forceinline__ float bf2f(u16 b) {
  union { uint32_t u; float f; } v; v.u = ((uint32_t)b) << 16;
  return v.f;
}

// ---------- weight fp32 -> padded bf16 ----------
__global__ void convert_w(const float* __restrict__ w, u16* __restrict__ out,
                          int Nr, int K, int Kp) {
  int idx = blockIdx.x * 256 + threadIdx.x;
  if (idx >= Nr * Kp) return;
  int r = idx / Kp, c = idx - r * Kp;
  float v = (c < K) ? w[(size_t)r * K + c] : 0.f;
  out[idx] = f2bf(v);
}

// ---------- CHW -> HWC bf16 transpose (32x32 tile over (c,x) for fixed (b,y)) ----------
__global__ void transpose_to_hwc(const float* __restrict__ in, u16* __restrict__ out,
                                 int C, int HH, int WW) {
  __shared__ float tile[32][33];
  const int xt = blockIdx.x, ct = blockIdx.y;
  const int bb = blockIdx.z / HH, y = blockIdx.z % HH;
  const int tx = threadIdx.x, ty = threadIdx.y;
  const int x0 = xt * 32, c0 = ct * 32;
#pragma unroll
  for (int i = 0; i < 4; ++i) {
    int c = c0 + ty + i * 8;
    tile[ty + i * 8][tx] = in[((size_t)(bb * C + c) * HH + y) * WW + x0 + tx];
  }
  __syncthreads();
#pragma unroll
  for (int i = 0; i < 4; ++i) {
    int x = x0 + ty + i * 8;
    out[((size_t)(bb * HH + y) * WW + x) * C + c0 + tx] = f2bf(tile[tx][ty + i * 8]);
  }
}

// ---------- one MLP layer: [32 rows] x K -> [32 rows] x NOUT, bf16 MFMA ----------
// A-frag: lane holds in[row = l&15][k = kk + 8*(l>>4) .. +7]  (8 contiguous bf16)
// B-frag: lane holds W[col = l&15 (+tile)][same 8 k]          (W stored [NOUT][K] bf16)
// C/D:    col = l&15, row = (l>>4)*4 + reg                    (m89/m91 verified)
template<int K, int NOUT, int LDI, int LDO, bool RELU>
__device__ __forceinline__ void mlp_layer(const u16* inB, u16* outB,
                                          const u16* __restrict__ Wb,
                                          const float* __restrict__ bias,
                                          int wave, int lane) {
  constexpr int NW  = NOUT / 4;      // cols per wave (4-wave N-split)
  constexpr int NJT = NW / 16;
  constexpr int JB  = (NJT >= 4) ? 4 : NJT;
  const int j0 = wave * NW;
  const int lr = lane & 15;
  const int lk = (lane >> 4) * 8;
  for (int jb = 0; jb < NJT; jb += JB) {
    f32x4 acc[JB][2];
#pragma unroll
    for (int jj = 0; jj < JB; ++jj)
#pragma unroll
      for (int rt = 0; rt < 2; ++rt)
        acc[jj][rt] = (f32x4){0.f, 0.f, 0.f, 0.f};
    const u16* wbase = Wb + (size_t)(j0 + jb * 16 + lr) * K + lk;
#pragma unroll 2
    for (int kk = 0; kk < K; kk += 32) {
      short8 Bf[JB];
#pragma unroll
      for (int jj = 0; jj < JB; ++jj)
        Bf[jj] = *(const short8*)(wbase + (size_t)jj * 16 * K + kk);
#pragma unroll
      for (int rt = 0; rt < 2; ++rt) {
        short8 Af = *(const short8*)(inB + (rt * 16 + lr) * LDI + kk + lk);
#pragma unroll
        for (int jj = 0; jj < JB; ++jj)
          acc[jj][rt] = __builtin_amdgcn_mfma_f32_16x16x32_bf16(Af, Bf[jj], acc[jj][rt], 0, 0, 0);
      }
    }
#pragma unroll
    for (int jj = 0; jj < JB; ++jj) {
      const int col = j0 + (jb + jj) * 16 + lr;
      const float bv = bias[col];
#pragma unroll
      for (int rt = 0; rt < 2; ++rt)
#pragma unroll
        for (int rr = 0; rr < 4; ++rr) {
          const int row = rt * 16 + (lane >> 4) * 4 + rr;
          float v = acc[jj][rt][rr] + bv;
          if (RELU) v = fmaxf(v, 0.f);
          outB[row * LDO + col] = f2bf(v);
        }
    }
  }
}

// ---------- fused main kernel: gather + 5-layer MLP per 32-row tile ----------
__global__ __launch_bounds__(256) void jiif_main(
    const float* __restrict__ coord,
    const u16* __restrict__ featT, const u16* __restrict__ hrT, const u16* __restrict__ lrT,
    const u16* __restrict__ W0b, const u16* __restrict__ W1b,
    const u16* __restrict__ W2b, const u16* __restrict__ W3b,
    const float* __restrict__ b0, const float* __restrict__ b1,
    const float* __restrict__ b2, const float* __restrict__ b3,
    const float* __restrict__ W4, const float* __restrict__ b4,
    float* __restrict__ preds) {
  extern __shared__ u16 lds[];
  const int tid = threadIdx.x;
  const int wave = tid >> 6, lane = tid & 63;
  const int m0 = blockIdx.x * 32;

  // ---- build X[32][416] in LDS ----
  {
    const int r = tid >> 3;       // local row 0..31
    const int g = tid & 7;        // 8 threads per row
    const int row = m0 + r;
    const int n = row & (NN - 1);
    const int bb = (row >> 14) & (BN - 1);
    const int k = row >> 15;      // sample index 0..3
    const float c0 = coord[((size_t)bb * NN + n) * 2 + 0];
    const float c1 = coord[((size_t)bb * NN + n) * 2 + 1];
    const float cy = c0 + ((k < 2) ? -1.f : 1.f) * (1.f / FH);
    const float cx = c1 + ((k & 1) ? 1.f : -1.f) * (1.f / FW);
    const float fy = rintf((cy + 1.f) * (FH * 0.5f) - 0.5f);
    const float fx = rintf((cx + 1.f) * (FW * 0.5f) - 0.5f);
    const bool vF = (fy >= 0.f) && (fy < (float)FH) && (fx >= 0.f) && (fx < (float)FW);
    const int iy = max(0, min(FH - 1, (int)fy));
    const int ix = max(0, min(FW - 1, (int)fx));
    const float gy = rintf((c0 + 1.f) * (GH * 0.5f) - 0.5f);
    const float gx = rintf((c1 + 1.f) * (GW * 0.5f) - 0.5f);
    const bool vH = (gy >= 0.f) && (gy < (float)GH) && (gx >= 0.f) && (gx < (float)GW);
    const int jy = max(0, min(GH - 1, (int)gy));
    const int jx = max(0, min(GW - 1, (int)gx));
    const u16* fp = featT + (size_t)((bb * FH + iy) * FW + ix) * CC;
    const u16* lp = lrT  + (size_t)((bb * FH + iy) * FW + ix) * CC;
    const u16* hp = hrT  + (size_t)((bb * GH + jy) * GW + jx) * CC;
    u16* xr = lds + OX + r * SX;
#pragma unroll
    for (int t = 0; t < 2; ++t) {
      const int c8 = g * 16 + t * 8;
      short8 fv = vF ? *(const short8*)(fp + c8) : (short8)0;
      short8 lv = vF ? *(const short8*)(lp + c8) : (short8)0;
      short8 hv = vH ? *(const short8*)(hp + c8) : (short8)0;
      *(short8*)(xr + c8) = fv;
      *(short8*)(xr + CC + c8) = hv;
      short8 dv;
#pragma unroll
      for (int e = 0; e < 8; ++e)
        dv[e] = (short)f2bf(bf2f((u16)hv[e]) - bf2f((u16)lv[e]));
      *(short8*)(xr + 2 * CC + c8) = dv;
    }
    if (g == 0) {
      const float qc0 = vF ? (-1.f + (float)(2 * iy + 1) * (1.f / FH)) : 0.f;
      const float qc1 = vF ? (-1.f + (float)(2 * ix + 1) * (1.f / FW)) : 0.f;
      xr[384] = f2bf((c0 - qc0) * (float)FH);
      xr[385] = f2bf((c1 - qc1) * (float)FW);
#pragma unroll
      for (int c = 386; c < K0P; ++c) xr[c] = 0;
    }
  }
  __syncthreads();

  mlp_layer<K0P, 1024, SX, S1, true>(lds + OX, lds + O1, W0b, b0, wave, lane);
  __syncthreads();
  mlp_layer<1024, 512, S1, S2, true>(lds + O1, lds + O2, W1b, b1, wave, lane);
  __syncthreads();
  mlp_layer<512, 256, S2, S3, true>(lds + O2, lds + OX, W2b, b2, wave, lane);
  __syncthreads();
  mlp_layer<256, 128, S3, S4, true>(lds + OX, lds + O2, W3b, b3, wave, lane);
  __syncthreads();

  // ---- layer 4: [32][128] @ W4^T -> [32][2], 4 partial threads per output ----
  {
    const int m = tid >> 3;
    const int sub = tid & 7;
    const int j = sub & 1;
    const int q = sub >> 1;           // 0..3 : 32-channel chunk
    const u16* h4 = lds + O2 + m * S4 + q * 32;
    const float* w4 = W4 + j * CC + q * 32;
    float s = 0.f;
#pragma unroll
    for (int c = 0; c < 32; ++c) s += bf2f(h4[c]) * w4[c];
    s += __shfl_xor(s, 2);
    s += __shfl_xor(s, 4);
    if (q == 0) preds[(size_t)(m0 + m) * 2 + j] = s + b4[j];
  }
}

// ---------- softmax-combine over the 4 samples ----------
__global__ void jiif_combine(const float* __restrict__ preds, float* __restrict__ out) {
  const int i = blockIdx.x * 256 + threadIdx.x;   // b*N + n
  if (i >= BN * NN) return;
  float p0[4], p1[4];
#pragma unroll
  for (int k = 0; k < 4; ++k) {
    p0[k] = preds[((size_t)k * BN * NN + i) * 2 + 0];
    p1[k] = preds[((size_t)k * BN * NN + i) * 2 + 1];
  }
  float mx = fmaxf(fmaxf(p1[0], p1[1]), fmaxf(p1[2], p1[3]));
  float se = 0.f, so = 0.f;
#pragma unroll
  for (int k = 0; k < 4; ++k) {
    float e = expf(p1[k] - mx);
    se += e;
    so += p0[k] * e;
  }
  out[i] = so / se;
}

extern "C" void kernel_launch(void* const* d_in, const int* in_sizes, int n_in,
                              void* d_out, int out_size, void* d_ws, size_t ws_size,
                              hipStream_t stream) {
  const float* feat  = (const float*)d_in[0];
  const float* coord = (const float*)d_in[1];
  const float* hr    = (const float*)d_in[2];
  const float* lr    = (const float*)d_in[3];
  const float* W0 = (const float*)d_in[4];  const float* b0 = (const float*)d_in[5];
  const float* W1 = (const float*)d_in[6];  const float* b1 = (const float*)d_in[7];
  const float* W2 = (const float*)d_in[8];  const float* b2 = (const float*)d_in[9];
  const float* W3 = (const float*)d_in[10]; const float* b3 = (const float*)d_in[11];
  const float* W4 = (const float*)d_in[12]; const float* b4 = (const float*)d_in[13];

  char* ws = (char*)d_ws;
  // 256B-aligned ws layout
  u16* W0b   = (u16*)(ws + 0);          // 1024*416*2  =   851968
  u16* W1b   = (u16*)(ws + 851968);     // 512*1024*2  =  1048576
  u16* W2b   = (u16*)(ws + 1900544);    // 256*512*2   =   262144
  u16* W3b   = (u16*)(ws + 2162688);    // 128*256*2   =    65536
  u16* featT = (u16*)(ws + 2228224);    // 2*64*64*128*2 = 2097152
  u16* hrT   = (u16*)(ws + 4325376);    // 2*256*256*128*2 = 33554432
  u16* lrT   = (u16*)(ws + 37879808);   // 2097152
  float* preds = (float*)(ws + 39976960); // 131072*2*4 = 1048576  -> total 41025536
  if (ws_size < 41025536) return;       // refuse to corrupt memory

  convert_w<<<1664, 256, 0, stream>>>(W0, W0b, 1024, 386, K0P);
  convert_w<<<2048, 256, 0, stream>>>(W1, W1b, 512, 1024, 1024);
  convert_w<<<512,  256, 0, stream>>>(W2, W2b, 256, 512, 512);
  convert_w<<<128,  256, 0, stream>>>(W3, W3b, 128, 256, 256);

  transpose_to_hwc<<<dim3(2, 4, 128), dim3(32, 8), 0, stream>>>(feat, featT, CC, FH, FW);
  transpose_to_hwc<<<dim3(8, 4, 512), dim3(32, 8), 0, stream>>>(hr,   hrT,   CC, GH, GW);
  transpose_to_hwc<<<dim3(2, 4, 128), dim3(32, 8), 0, stream>>>(lr,   lrT,   CC, FH, FW);

  (void)hipFuncSetAttribute((const void*)jiif_main,
                            hipFuncAttributeMaxDynamicSharedMemorySize, LDS_ELEMS * 2);
  jiif_main<<<M_TOTAL / 32, 256, LDS_ELEMS * 2, stream>>>(
      coord, featT, hrT, lrT, W0b, W1b, W2b, W3b, b0, b1, b2, b3, W4, b4, preds);

  jiif_combine<<<(BN * NN + 255) / 256, 256, 0, stream>>>(preds, (float*)d_out);
}

// Round 2
// 371.487 us; speedup vs baseline: 2.6841x; 2.6841x over previous
//
#include <hip/hip_runtime.h>
#include <cstdint>

typedef unsigned short u16;
typedef __attribute__((ext_vector_type(8))) _Float16 half8;  // 8 fp16 in 4 VGPRs
typedef __attribute__((ext_vector_type(4))) float    f32x4;

#define BN 2
#define NN 16384
#define FH 64
#define FW 64
#define GH 256
#define GW 256
#define CC 128
#define K0P 416              // 386 padded to 13*32
#define M_TOTAL (4*BN*NN)    // 131072
#define MROWS 64             // rows per block
#define NBLK (M_TOTAL/MROWS) // 2048

// LDS strides (fp16 elems). byte stride/4 % 32 in {4,20} -> full 32-bank coverage, 2-way (free)
#define SX 424               // X region stride   (848B)
#define SB 520               // H1half/H2 stride  (1040B)
#define S3 264               // H3 stride (in X region)
#define S4 136               // H4 stride (in B region)
#define OB (MROWS*SX)        // 27136 elems
#define LDS_ELEMS (OB + MROWS*SB)  // 60416 elems = 120832 B

__device__ __forceinline__ half8 zero8() {
  half8 z;
#pragma unroll
  for (int e = 0; e < 8; ++e) z[e] = (_Float16)0.f;
  return z;
}

// ---------- weight fp32 -> packed fp16 MFMA-fragment tiles ----------
// out[((jt*KT + kt)*64 + lane)*8 + e] = W[jt*16 + (lane&15)][kt*32 + (lane>>4)*8 + e]
__global__ void pack_w(const float* __restrict__ w, _Float16* __restrict__ out,
                       int NOUT, int K, int KT) {
  int idx = blockIdx.x * 256 + threadIdx.x;        // one 8-elem lane chunk
  int total = (NOUT / 16) * KT * 64;
  if (idx >= total) return;
  int l = idx & 63;
  int t = idx >> 6;
  int kt = t % KT;
  int jt = t / KT;
  int row = jt * 16 + (l & 15);
  int k0 = kt * 32 + (l >> 4) * 8;
  _Float16* o = out + (size_t)idx * 8;
#pragma unroll
  for (int e = 0; e < 8; ++e) {
    int k = k0 + e;
    float v = (k < K) ? w[(size_t)row * K + k] : 0.f;
    o[e] = (_Float16)v;
  }
}

// ---------- CHW -> HWC fp16 transpose ----------
__global__ void transpose_to_hwc(const float* __restrict__ in, _Float16* __restrict__ out,
                                 int C, int HH, int WW) {
  __shared__ float tile[32][33];
  const int xt = blockIdx.x, ct = blockIdx.y;
  const int bb = blockIdx.z / HH, y = blockIdx.z % HH;
  const int tx = threadIdx.x, ty = threadIdx.y;
  const int x0 = xt * 32, c0 = ct * 32;
#pragma unroll
  for (int i = 0; i < 4; ++i) {
    int c = c0 + ty + i * 8;
    tile[ty + i * 8][tx] = in[((size_t)(bb * C + c) * HH + y) * WW + x0 + tx];
  }
  __syncthreads();
#pragma unroll
  for (int i = 0; i < 4; ++i) {
    int x = x0 + ty + i * 8;
    out[((size_t)(bb * HH + y) * WW + x) * C + c0 + tx] = (_Float16)tile[tx][ty + i * 8];
  }
}

// ---------- MFMA tile-GEMM: acc[JT][4] += in[64 x 32*KT] @ W-tiles ----------
// A-frag: lane -> in[rt*16 + (l&15)][kt*32 + 8*(l>>4) .. +7]
// B-frag: packed contiguous 1KB per (jj,kt) tile
template<int KT, int JT>
__device__ __forceinline__ void gemm_block(f32x4 (*acc)[4],
    const _Float16* lin, int ldi,
    const _Float16* __restrict__ Wt, int wTileStride,   // elems between jj tiles
    int lane) {
  const int lr = lane & 15, lk = (lane >> 4) * 8;
#pragma unroll 2
  for (int kt = 0; kt < KT; ++kt) {
    half8 B[JT];
#pragma unroll
    for (int jj = 0; jj < JT; ++jj)
      B[jj] = *(const half8*)(Wt + (size_t)jj * wTileStride + (kt * 64 + lane) * 8);
    half8 A[4];
#pragma unroll
    for (int rt = 0; rt < 4; ++rt)
      A[rt] = *(const half8*)(lin + (rt * 16 + lr) * ldi + kt * 32 + lk);
#pragma unroll
    for (int jj = 0; jj < JT; ++jj)
#pragma unroll
      for (int rt = 0; rt < 4; ++rt)
        acc[jj][rt] = __builtin_amdgcn_mfma_f32_16x16x32_f16(A[rt], B[jj], acc[jj][rt], 0, 0, 0);
  }
}

// C/D layout: col = l&15, row = (l>>4)*4 + reg  (m89/m91 verified, dtype-independent)
template<int JT, bool RELU>
__device__ __forceinline__ void store_h(const f32x4 (*acc)[4], _Float16* lout, int ldo,
                                        int colbase, const float* __restrict__ bias, int lane) {
  const int lr = lane & 15, rhi = (lane >> 4) * 4;
#pragma unroll
  for (int jj = 0; jj < JT; ++jj) {
    const int col = colbase + jj * 16 + lr;
    const float bv = bias[col];
#pragma unroll
    for (int rt = 0; rt < 4; ++rt)
#pragma unroll
      for (int rr = 0; rr < 4; ++rr) {
        float v = acc[jj][rt][rr] + bv;
        if (RELU) v = fmaxf(v, 0.f);
        lout[(rt * 16 + rhi + rr) * ldo + col] = (_Float16)v;
      }
  }
}

// ---------- fused main kernel ----------
__global__ __launch_bounds__(512, 2) void jiif_main(
    const float* __restrict__ coord,
    const _Float16* __restrict__ featT, const _Float16* __restrict__ hrT,
    const _Float16* __restrict__ lrT,
    const _Float16* __restrict__ W0p, const _Float16* __restrict__ W1p,
    const _Float16* __restrict__ W2p, const _Float16* __restrict__ W3p,
    const float* __restrict__ b0, const float* __restrict__ b1,
    const float* __restrict__ b2, const float* __restrict__ b3,
    const float* __restrict__ W4, const float* __restrict__ b4,
    float* __restrict__ preds) {
  extern __shared__ _Float16 lds[];
  const int tid = threadIdx.x;
  const int wave = tid >> 6, lane = tid & 63;
  const int m0 = blockIdx.x * MROWS;
  _Float16* X  = lds;        // [64][424]; later H3 [64][264]
  _Float16* Hb = lds + OB;   // [64][520]; later H4 [64][136]

  // ---- gather: build X[64][416] ----
  {
    const int r = tid >> 3;       // 0..63
    const int g = tid & 7;        // 8 threads per row
    const int row = m0 + r;
    const int n = row & (NN - 1);
    const int bb = (row >> 14) & (BN - 1);
    const int k = row >> 15;      // offset index 0..3
    const float c0 = coord[((size_t)bb * NN + n) * 2 + 0];
    const float c1 = coord[((size_t)bb * NN + n) * 2 + 1];
    const float cy = c0 + ((k < 2) ? -1.f : 1.f) * (1.f / FH);
    const float cx = c1 + ((k & 1) ? 1.f : -1.f) * (1.f / FW);
    const float fy = rintf((cy + 1.f) * (FH * 0.5f) - 0.5f);
    const float fx = rintf((cx + 1.f) * (FW * 0.5f) - 0.5f);
    const bool vF = (fy >= 0.f) && (fy < (float)FH) && (fx >= 0.f) && (fx < (float)FW);
    const int iy = max(0, min(FH - 1, (int)fy));
    const int ix = max(0, min(FW - 1, (int)fx));
    const float gy = rintf((c0 + 1.f) * (GH * 0.5f) - 0.5f);
    const float gx = rintf((c1 + 1.f) * (GW * 0.5f) - 0.5f);
    const bool vH = (gy >= 0.f) && (gy < (float)GH) && (gx >= 0.f) && (gx < (float)GW);
    const int jy = max(0, min(GH - 1, (int)gy));
    const int jx = max(0, min(GW - 1, (int)gx));
    const _Float16* fp = featT + (size_t)((bb * FH + iy) * FW + ix) * CC;
    const _Float16* lp = lrT  + (size_t)((bb * FH + iy) * FW + ix) * CC;
    const _Float16* hp = hrT  + (size_t)((bb * GH + jy) * GW + jx) * CC;
    _Float16* xr = X + r * SX;
#pragma unroll
    for (int t = 0; t < 2; ++t) {
      const int c8 = g * 16 + t * 8;
      half8 fv = vF ? *(const half8*)(fp + c8) : zero8();
      half8 lv = vF ? *(const half8*)(lp + c8) : zero8();
      half8 hv = vH ? *(const half8*)(hp + c8) : zero8();
      *(half8*)(xr + c8) = fv;
      *(half8*)(xr + CC + c8) = hv;
      half8 dv = hv - lv;
      *(half8*)(xr + 2 * CC + c8) = dv;
    }
    if (g == 0) {
      const float qc0 = vF ? (-1.f + (float)(2 * iy + 1) * (1.f / FH)) : 0.f;
      const float qc1 = vF ? (-1.f + (float)(2 * ix + 1) * (1.f / FW)) : 0.f;
      xr[384] = (_Float16)((c0 - qc0) * (float)FH);
      xr[385] = (_Float16)((c1 - qc1) * (float)FW);
#pragma unroll
      for (int c = 386; c < K0P; ++c) xr[c] = (_Float16)0.f;
    }
  }
  __syncthreads();

  // ---- layer 0 (K=416 -> 1024) in 2 col-halves, fused with layer 1 (K=1024 -> 512) ----
  f32x4 acc2[4][4];
#pragma unroll
  for (int a = 0; a < 4; ++a)
#pragma unroll
    for (int b = 0; b < 4; ++b) acc2[a][b] = (f32x4){0.f, 0.f, 0.f, 0.f};

#pragma unroll 1
  for (int p = 0; p < 2; ++p) {
    f32x4 acc0[4][4];
#pragma unroll
    for (int a = 0; a < 4; ++a)
#pragma unroll
      for (int b = 0; b < 4; ++b) acc0[a][b] = (f32x4){0.f, 0.f, 0.f, 0.f};
    // H1 half p: cols [p*512, p*512+512), this wave: 4 tiles at p*32 + wave*4
    gemm_block<13, 4>(acc0, X, SX, W0p + (size_t)(p * 32 + wave * 4) * 13 * 512, 13 * 512, lane);
    store_h<4, true>(acc0, Hb, SB, wave * 64, b0 + p * 512, lane);
    __syncthreads();
    // layer 1 partial: K-chunk [p*512, p*512+512) from Hb
    gemm_block<16, 4>(acc2, Hb, SB,
                      W1p + (size_t)(wave * 4) * 32 * 512 + (size_t)(p * 16) * 512, 32 * 512, lane);
    __syncthreads();
  }
  store_h<4, true>(acc2, Hb, SB, wave * 64, b1, lane);   // H2 [64][512] -> Hb
  __syncthreads();

  // ---- layer 2: K=512 -> 256, H3 -> X region ----
  {
    f32x4 acc3[2][4];
#pragma unroll
    for (int a = 0; a < 2; ++a)
#pragma unroll
      for (int b = 0; b < 4; ++b) acc3[a][b] = (f32x4){0.f, 0.f, 0.f, 0.f};
    gemm_block<16, 2>(acc3, Hb, SB, W2p + (size_t)(wave * 2) * 16 * 512, 16 * 512, lane);
    __syncthreads();                 // Hb fully read before X? (X is output region, Hb is input: sync above store)
    store_h<2, true>(acc3, X, S3, wave * 32, b2, lane);
    __syncthreads();
  }

  // ---- layer 3: K=256 -> 128, H4 -> Hb region ----
  {
    f32x4 acc4[1][4];
#pragma unroll
    for (int b = 0; b < 4; ++b) acc4[0][b] = (f32x4){0.f, 0.f, 0.f, 0.f};
    gemm_block<8, 1>(acc4, X, S3, W3p + (size_t)wave * 8 * 512, 8 * 512, lane);
    __syncthreads();
    store_h<1, true>(acc4, Hb, S4, wave * 16, b3, lane);
    __syncthreads();
  }

  // ---- layer 4: [64][128] @ W4^T -> [64][2] ----
  {
    const int m = tid >> 3;
    const int sub = tid & 7;
    const int j = sub & 1;
    const int q = sub >> 1;           // 0..3 : 32-channel chunk
    const _Float16* h4 = Hb + m * S4 + q * 32;
    const float* w4 = W4 + j * CC + q * 32;
    float s = 0.f;
#pragma unroll
    for (int c = 0; c < 32; ++c) s += (float)h4[c] * w4[c];
    s += __shfl_xor(s, 2);
    s += __shfl_xor(s, 4);
    if (q == 0) preds[(size_t)(m0 + m) * 2 + j] = s + b4[j];
  }
}

// ---------- softmax-combine over the 4 samples ----------
__global__ void jiif_combine(const float* __restrict__ preds, float* __restrict__ out) {
  const int i = blockIdx.x * 256 + threadIdx.x;   // b*N + n
  if (i >= BN * NN) return;
  float p0[4], p1[4];
#pragma unroll
  for (int k = 0; k < 4; ++k) {
    p0[k] = preds[((size_t)k * BN * NN + i) * 2 + 0];
    p1[k] = preds[((size_t)k * BN * NN + i) * 2 + 1];
  }
  float mx = fmaxf(fmaxf(p1[0], p1[1]), fmaxf(p1[2], p1[3]));
  float se = 0.f, so = 0.f;
#pragma unroll
  for (int k = 0; k < 4; ++k) {
    float e = expf(p1[k] - mx);
    se += e;
    so += p0[k] * e;
  }
  out[i] = so / se;
}

extern "C" void kernel_launch(void* const* d_in, const int* in_sizes, int n_in,
                              void* d_out, int out_size, void* d_ws, size_t ws_size,
                              hipStream_t stream) {
  const float* feat  = (const float*)d_in[0];
  const float* coord = (const float*)d_in[1];
  const float* hr    = (const float*)d_in[2];
  const float* lr    = (const float*)d_in[3];
  const float* W0 = (const float*)d_in[4];  const float* b0 = (const float*)d_in[5];
  const float* W1 = (const float*)d_in[6];  const float* b1 = (const float*)d_in[7];
  const float* W2 = (const float*)d_in[8];  const float* b2 = (const float*)d_in[9];
  const float* W3 = (const float*)d_in[10]; const float* b3 = (const float*)d_in[11];
  const float* W4 = (const float*)d_in[12]; const float* b4 = (const float*)d_in[13];

  char* ws = (char*)d_ws;
  _Float16* W0p   = (_Float16*)(ws + 0);          // 1024*416*2  =   851968
  _Float16* W1p   = (_Float16*)(ws + 851968);     // 512*1024*2  =  1048576
  _Float16* W2p   = (_Float16*)(ws + 1900544);    // 256*512*2   =   262144
  _Float16* W3p   = (_Float16*)(ws + 2162688);    // 128*256*2   =    65536
  _Float16* featT = (_Float16*)(ws + 2228224);    // 2*64*64*128*2 = 2097152
  _Float16* hrT   = (_Float16*)(ws + 4325376);    // 2*256*256*128*2 = 33554432
  _Float16* lrT   = (_Float16*)(ws + 37879808);   // 2097152
  float* preds    = (float*)(ws + 39976960);      // 131072*2*4 = 1048576 -> total 41025536
  if (ws_size < 41025536) return;

  pack_w<<<208, 256, 0, stream>>>(W0, W0p, 1024, 386, 13);
  pack_w<<<256, 256, 0, stream>>>(W1, W1p, 512, 1024, 32);
  pack_w<<<64,  256, 0, stream>>>(W2, W2p, 256, 512, 16);
  pack_w<<<16,  256, 0, stream>>>(W3, W3p, 128, 256, 8);

  transpose_to_hwc<<<dim3(2, 4, 128), dim3(32, 8), 0, stream>>>(feat, featT, CC, FH, FW);
  transpose_to_hwc<<<dim3(8, 4, 512), dim3(32, 8), 0, stream>>>(hr,   hrT,   CC, GH, GW);
  transpose_to_hwc<<<dim3(2, 4, 128), dim3(32, 8), 0, stream>>>(lr,   lrT,   CC, FH, FW);

  (void)hipFuncSetAttribute((const void*)jiif_main,
                            hipFuncAttributeMaxDynamicSharedMemorySize, LDS_ELEMS * 2);
  jiif_main<<<NBLK, 512, LDS_ELEMS * 2, stream>>>(
      coord, featT, hrT, lrT, W0p, W1p, W2p, W3p, b0, b1, b2, b3, W4, b4, preds);

  jiif_combine<<<(BN * NN + 255) / 256, 256, 0, stream>>>(preds, (float*)d_out);
}